// Round 14
// baseline (314.623 us; speedup 1.0000x reference)
//
#include <hip/hip_runtime.h>
#include <cstddef>
#include <cstdint>

#define F 128
#define C_OUT 10
#define SB 256   // scan block size

typedef short bf16x8 __attribute__((ext_vector_type(8)));
typedef float f32x4  __attribute__((ext_vector_type(4)));
typedef float f32x2  __attribute__((ext_vector_type(2)));

__device__ __forceinline__ unsigned short bf16_rne(float f) {
  unsigned u = __float_as_uint(f);
  return (unsigned short)((u + 0x7FFFu + ((u >> 16) & 1u)) >> 16);
}

// ---------------- GRU weight evolution (both layers, single-bf16 RNE) + zero counts ----
__global__ void gru_evolve2_k(const float* __restrict__ W01, const float* __restrict__ wih1,
                              const float* __restrict__ whh1, const float* __restrict__ bih1,
                              const float* __restrict__ bhh1,
                              const float* __restrict__ W02, const float* __restrict__ wih2,
                              const float* __restrict__ whh2, const float* __restrict__ bih2,
                              const float* __restrict__ bhh2,
                              unsigned short* __restrict__ Bhi1, unsigned short* __restrict__ Bhi2,
                              int* __restrict__ counts, int n) {
  if ((int)blockIdx.x >= 128) {
    int i = ((int)blockIdx.x - 128) * SB + threadIdx.x;
    if (i < n) counts[i] = 0;
    return;
  }
  int t = blockIdx.x * 256 + threadIdx.x;     // 0..32767
  int layer = t >> 14;
  int tt = t & 16383;
  const float* W0  = layer ? W02  : W01;
  const float* wih = layer ? wih2 : wih1;
  const float* whh = layer ? whh2 : whh1;
  const float* bih = layer ? bih2 : bih1;
  const float* bhh = layer ? bhh2 : bhh1;
  unsigned short* Bhi = layer ? Bhi2 : Bhi1;
  int i = tt >> 7, j = tt & 127;      // i = k (feature) index, j = w_col index
  const float4* w0r = (const float4*)(W0 + (size_t)i * F);
  float gi[3], gh[3];
#pragma unroll
  for (int g = 0; g < 3; ++g) {
    const float4* wr = (const float4*)(wih + (size_t)(g * F + j) * F);
    const float4* hr = (const float4*)(whh + (size_t)(g * F + j) * F);
    float si = 0.f, sh = 0.f;
    for (int k = 0; k < F / 4; ++k) {
      float4 a = w0r[k];
      float4 b = wr[k];
      float4 c = hr[k];
      si += a.x * b.x + a.y * b.y + a.z * b.z + a.w * b.w;
      sh += a.x * c.x + a.y * c.y + a.z * c.z + a.w * c.w;
    }
    gi[g] = si + bih[g * F + j];
    gh[g] = sh + bhh[g * F + j];
  }
  float r = 1.0f / (1.0f + expf(-(gi[0] + gh[0])));
  float z = 1.0f / (1.0f + expf(-(gi[1] + gh[1])));
  float nn = tanhf(gi[2] + r * gh[2]);
  float val = (1.0f - z) * nn + z * W0[(size_t)i * F + j];

  int kstep = i >> 5, kl = i & 31;
  int lane = (kl >> 3) * 16 + (j & 15);
  int tile = j >> 4;
  int idx = ((kstep * 8 + tile) * 64 + lane) * 8 + (kl & 7);
  Bhi[idx] = bf16_rne(val);
}

// ---------------- CSR build ----------------
__global__ void count_rank_k(const int* __restrict__ dst, int* __restrict__ counts,
                             int* __restrict__ rank, int E) {
  int e = blockIdx.x * blockDim.x + threadIdx.x;
  if (e < E) rank[e] = atomicAdd(&counts[dst[e]], 1);
}

__global__ void scan_local_k(const int* __restrict__ counts, int* __restrict__ incl,
                             int* __restrict__ blocksum, int n) {
  __shared__ int sh[SB];
  int gid = blockIdx.x * SB + threadIdx.x;
  int v = (gid < n) ? counts[gid] : 0;
  sh[threadIdx.x] = v;
  __syncthreads();
  for (int off = 1; off < SB; off <<= 1) {
    int t = 0;
    if ((int)threadIdx.x >= off) t = sh[threadIdx.x - off];
    __syncthreads();
    if ((int)threadIdx.x >= off) sh[threadIdx.x] += t;
    __syncthreads();
  }
  if (gid < n) incl[gid] = sh[threadIdx.x];
  if (threadIdx.x == SB - 1) blocksum[blockIdx.x] = sh[SB - 1];
}

__global__ void scan_finish_k(const int* __restrict__ counts, const int* __restrict__ incl,
                              const int* __restrict__ blocksum, int* __restrict__ rowptr,
                              float* __restrict__ dinv, int n, int nb) {
  __shared__ int sh[SB];
  __shared__ int orig[SB];
  int v = ((int)threadIdx.x < nb) ? blocksum[threadIdx.x] : 0;
  sh[threadIdx.x] = v;
  orig[threadIdx.x] = v;
  __syncthreads();
  for (int off = 1; off < SB; off <<= 1) {
    int t = 0;
    if ((int)threadIdx.x >= off) t = sh[threadIdx.x - off];
    __syncthreads();
    if ((int)threadIdx.x >= off) sh[threadIdx.x] += t;
    __syncthreads();
  }
  int myoff = sh[blockIdx.x] - orig[blockIdx.x];
  int gid = blockIdx.x * SB + threadIdx.x;
  if (gid >= n) return;
  int c = counts[gid];
  int inc = myoff + incl[gid];
  rowptr[gid] = inc - c;
  dinv[gid] = rsqrtf((float)c + 1.0f);
  if (gid == n - 1) rowptr[n] = inc;
}

// fill stores PRE-SHIFTED src (src<<6 = byte offset of the 64B plane row).
__device__ __forceinline__ void fill_body(int bid, const int* __restrict__ src,
                                          const int* __restrict__ dst,
                                          const int* __restrict__ rank,
                                          const int* __restrict__ rowptr,
                                          int* __restrict__ csr_src, int E) {
  int e = bid * 256 + (int)threadIdx.x;
  if (e < E) {
    int d = dst[e];
    csr_src[rowptr[d] + rank[e]] = src[e] << 6;
  }
}

// ---------------- MFMA GEMM: two fp8 planes (cols 0-63 / 64-127), 64 B rows ----------
// Transposed MFMA: D = W' (A) x X^T (B); lane owns x_row = lane&15, 4 consecutive
// w_cols per tile. Single-bf16 inputs (RNE) -- error well under the bf16
// comparison floor. Epilogue: fp8 e4m3 encode (HW cvt_pk_fp8_f32), col c ->
// plane c>>6, dword (c&63)>>2.
__device__ __forceinline__ void gemm_body(int bid, const float* __restrict__ X,
                                          const unsigned short* __restrict__ Bhi,
                                          const float* __restrict__ dinv,
                                          unsigned* __restrict__ Y0,
                                          unsigned* __restrict__ Y1, int nrows) {
  int wid = bid * 4 + ((int)threadIdx.x >> 6);
  int lane = threadIdx.x & 63;
  int ng = (nrows + 15) >> 4;
  if (wid >= ng) return;
  int g = __builtin_amdgcn_readfirstlane(wid);
  int q = lane >> 4, m = lane & 15;
  int rowA = g * 16 + m;
  if (rowA >= nrows) rowA = nrows - 1;

  f32x4 acc[8];
#pragma unroll
  for (int t = 0; t < 8; ++t) { acc[t].x = 0.f; acc[t].y = 0.f; acc[t].z = 0.f; acc[t].w = 0.f; }

#pragma unroll
  for (int s = 0; s < 4; ++s) {
    const float* xp = X + (size_t)rowA * F + s * 32 + q * 8;
    float4 xa = *(const float4*)xp;
    float4 xb = *(const float4*)(xp + 4);
    float xv[8] = {xa.x, xa.y, xa.z, xa.w, xb.x, xb.y, xb.z, xb.w};
    bf16x8 xh;
#pragma unroll
    for (int j = 0; j < 8; ++j) xh[j] = (short)bf16_rne(xv[j]);
#pragma unroll
    for (int t = 0; t < 8; ++t) {
      size_t boff = ((size_t)(s * 8 + t) * 64 + lane) * 8;
      bf16x8 wh = *(const bf16x8*)(Bhi + boff);
      acc[t] = __builtin_amdgcn_mfma_f32_16x16x32_bf16(wh, xh, acc[t], 0, 0, 0);
    }
  }

  int row = g * 16 + m;
  if (row < nrows) {
    float dd = dinv[row];
    unsigned* p0 = Y0 + (size_t)row * 16 + q;   // plane rows = 16 dwords
    unsigned* p1 = Y1 + (size_t)row * 16 + q;
#pragma unroll
    for (int t = 0; t < 8; ++t) {
      int p = __builtin_amdgcn_cvt_pk_fp8_f32(dd * acc[t].x, dd * acc[t].y, 0, false);
      p = __builtin_amdgcn_cvt_pk_fp8_f32(dd * acc[t].z, dd * acc[t].w, p, true);
      if (t < 4) p0[(t & 3) * 4] = (unsigned)p;
      else       p1[(t & 3) * 4] = (unsigned)p;
    }
  }
}

__global__ void gemm_mfma_k(const float* __restrict__ X, const unsigned short* __restrict__ Bhi,
                            const float* __restrict__ dinv, unsigned* __restrict__ Y0,
                            unsigned* __restrict__ Y1, int nrows) {
  gemm_body(blockIdx.x, X, Bhi, dinv, Y0, Y1, nrows);
}

__global__ void fill_gemm_k(const float* __restrict__ X, const unsigned short* __restrict__ Bhi,
                            const float* __restrict__ dinv, unsigned* __restrict__ Y0,
                            unsigned* __restrict__ Y1, int nrows, int ngemm,
                            const int* __restrict__ src, const int* __restrict__ dst,
                            const int* __restrict__ rank, const int* __restrict__ rowptr,
                            int* __restrict__ csr_src, int E) {
  if ((int)blockIdx.x < ngemm)
    gemm_body(blockIdx.x, X, Bhi, dinv, Y0, Y1, nrows);
  else
    fill_body((int)blockIdx.x - ngemm, src, dst, rank, rowptr, csr_src, E);
}

// ---------------- gather pass: one 3.2 MB plane (fits per-XCD L2) ------------------
// One wave per node; quarter q (16 lanes) handles edges b+q+4k; lane m loads the
// dword = cols {plane*64 + m*4 .. +3}. csr indices: 4 scalar loads + 3 cndmask
// select (fixes R9's vector-index regression). Column sums are COMPLETE within a
// plane, so relu per pass is exact. MODE 0: write h cols [PASS*64, +64).
// MODE 1: write partial class dots to pacc. MODE 2: add pacc + bias, log_softmax.
template <int PASS, int MODE>
__global__ void agg_pass_k(const int* __restrict__ rowptr, const int* __restrict__ csr_src,
                           const float* __restrict__ dinv, const unsigned* __restrict__ plane,
                           float* __restrict__ hout,
                           const float* __restrict__ lw, const float* __restrict__ lb,
                           float* __restrict__ pacc, float* __restrict__ outp, int n) {
  int wave = (int)((blockIdx.x * blockDim.x + threadIdx.x) >> 6);
  int lane = threadIdx.x & 63;
  if (wave >= n) return;
  int node = __builtin_amdgcn_readfirstlane(wave);
  int m = lane & 15;
  float dd = dinv[node];
  const char* __restrict__ cb = (const char*)plane;   // row = 64 bytes
  unsigned loff = (unsigned)(m << 2);
  f32x2 a0 = {0.f, 0.f}, a1 = {0.f, 0.f};
  f32x2 b0 = {0.f, 0.f}, b1 = {0.f, 0.f};

#define SEL4(A, B, C, D) ((lane & 32) ? ((lane & 16) ? (D) : (C)) : ((lane & 16) ? (B) : (A)))
#define DEC(U, P, Q)                                            \
  do {                                                          \
    (P) += __builtin_amdgcn_cvt_pk_f32_fp8((int)(U), false);    \
    (Q) += __builtin_amdgcn_cvt_pk_f32_fp8((int)(U), true);     \
  } while (0)

  // self-loop: quarter 0 only
  {
    unsigned u = *(const unsigned*)(cb + ((((unsigned)node) << 6) | loff));
    if (lane >= 16) u = 0u;
    DEC(u, a0, a1);
  }

  int b = rowptr[node], e = rowptr[node + 1];
  int i = b;
  // 16 edges / iter = 4 wave-loads (each load covers 4 edges x 64 B)
  for (; i + 16 <= e; i += 16) {
    int s0 = csr_src[i + 0],  s1 = csr_src[i + 1],  s2 = csr_src[i + 2],  s3 = csr_src[i + 3];
    int s4 = csr_src[i + 4],  s5 = csr_src[i + 5],  s6 = csr_src[i + 6],  s7 = csr_src[i + 7];
    int s8 = csr_src[i + 8],  s9 = csr_src[i + 9],  sA = csr_src[i + 10], sB = csr_src[i + 11];
    int sC = csr_src[i + 12], sD = csr_src[i + 13], sE = csr_src[i + 14], sF = csr_src[i + 15];
    unsigned o0 = ((unsigned)SEL4(s0, s1, s2, s3)) | loff;
    unsigned o1 = ((unsigned)SEL4(s4, s5, s6, s7)) | loff;
    unsigned o2 = ((unsigned)SEL4(s8, s9, sA, sB)) | loff;
    unsigned o3 = ((unsigned)SEL4(sC, sD, sE, sF)) | loff;
    unsigned u0 = *(const unsigned*)(cb + o0);
    unsigned u1 = *(const unsigned*)(cb + o1);
    unsigned u2 = *(const unsigned*)(cb + o2);
    unsigned u3 = *(const unsigned*)(cb + o3);
    DEC(u0, a0, a1);
    DEC(u1, b0, b1);
    DEC(u2, a0, a1);
    DEC(u3, b0, b1);
  }
  // 4-edge tail (clamped + zeroed)
  for (; i < e; i += 4) {
    int e1 = e - 1;
    int c1 = (i + 1 < e) ? i + 1 : e1;
    int c2 = (i + 2 < e) ? i + 2 : e1;
    int c3 = (i + 3 < e) ? i + 3 : e1;
    int s0 = csr_src[i], s1 = csr_src[c1], s2 = csr_src[c2], s3 = csr_src[c3];
    unsigned o = ((unsigned)SEL4(s0, s1, s2, s3)) | loff;
    unsigned u = *(const unsigned*)(cb + o);
    int idx = i + (lane >> 4);
    if (idx >= e) u = 0u;
    DEC(u, a0, a1);
  }
#undef DEC
#undef SEL4
  a0 += b0;
  a1 += b1;

  // combine quarters: all lanes end with full column sums
  a0.x += __shfl_xor(a0.x, 16); a0.y += __shfl_xor(a0.y, 16);
  a1.x += __shfl_xor(a1.x, 16); a1.y += __shfl_xor(a1.y, 16);
  a0.x += __shfl_xor(a0.x, 32); a0.y += __shfl_xor(a0.y, 32);
  a1.x += __shfl_xor(a1.x, 32); a1.y += __shfl_xor(a1.y, 32);

  float h0 = fmaxf(dd * a0.x, 0.f);
  float h1 = fmaxf(dd * a0.y, 0.f);
  float h2 = fmaxf(dd * a1.x, 0.f);
  float h3 = fmaxf(dd * a1.y, 0.f);

  if (MODE == 0) {
    if (lane < 16)
      *(float4*)(hout + (size_t)node * F + PASS * 64 + m * 4) = make_float4(h0, h1, h2, h3);
  } else {
    float acc[C_OUT];
#pragma unroll
    for (int c = 0; c < C_OUT; ++c) {
      float4 w = *(const float4*)(lw + (size_t)c * F + PASS * 64 + m * 4);
      float v = h0 * w.x + h1 * w.y + h2 * w.z + h3 * w.w;
      v += __shfl_xor(v, 1); v += __shfl_xor(v, 2);
      v += __shfl_xor(v, 4); v += __shfl_xor(v, 8);
      acc[c] = v;
    }
    if (MODE == 1) {
#pragma unroll
      for (int c = 0; c < C_OUT; ++c)
        if (lane == c) pacc[(size_t)node * C_OUT + c] = acc[c];
    } else {
#pragma unroll
      for (int c = 0; c < C_OUT; ++c)
        acc[c] += pacc[(size_t)node * C_OUT + c] + lb[c];   // uniform -> s_load
      float mx = acc[0];
#pragma unroll
      for (int c = 1; c < C_OUT; ++c) mx = fmaxf(mx, acc[c]);
      float s = 0.f;
#pragma unroll
      for (int c = 0; c < C_OUT; ++c) s += expf(acc[c] - mx);
      float lse = mx + logf(s);
#pragma unroll
      for (int c = 0; c < C_OUT; ++c)
        if (lane == c) outp[(size_t)node * C_OUT + c] = acc[c] - lse;
    }
  }
}

extern "C" void kernel_launch(void* const* d_in, const int* in_sizes, int n_in,
                              void* d_out, int out_size, void* d_ws, size_t ws_size,
                              hipStream_t stream) {
  const float* x    = (const float*)d_in[0];
  const int*   ei   = (const int*)d_in[1];
  const float* W1   = (const float*)d_in[2];
  const float* wih1 = (const float*)d_in[3];
  const float* whh1 = (const float*)d_in[4];
  const float* bih1 = (const float*)d_in[5];
  const float* bhh1 = (const float*)d_in[6];
  const float* W2   = (const float*)d_in[7];
  const float* wih2 = (const float*)d_in[8];
  const float* whh2 = (const float*)d_in[9];
  const float* bih2 = (const float*)d_in[10];
  const float* bhh2 = (const float*)d_in[11];
  const float* lw   = (const float*)d_in[12];
  const float* lb   = (const float*)d_in[13];
  float* out = (float*)d_out;

  int N = in_sizes[0] / F;
  int E = in_sizes[1] / 2;
  const int* src = ei;
  const int* dst = ei + E;
  int nb = (N + SB - 1) / SB;   // 196 (must be <= 256)
  int ng = (N + 15) / 16;
  int ngemm = (ng + 3) / 4;
  int nfill = (E + 255) / 256;
  int nagg = (N + 3) / 4;

  float* ws = (float*)d_ws;
  unsigned* plane0 = (unsigned*)ws;              // N*16 dwords (fp8 cols 0-63)
  unsigned* plane1 = plane0 + (size_t)N * 16;    // N*16 dwords (fp8 cols 64-127)
  float* bufB = (float*)(plane1 + (size_t)N * 16);  // N*F floats (h)
  float* dinv = bufB + (size_t)N * F;            // N
  unsigned short* Bhi1 = (unsigned short*)(dinv + N);  // 16384
  unsigned short* Bhi2 = Bhi1 + F * F;                 // 16384
  int* counts = (int*)(Bhi2 + F * F);            // N
  int* rowptr = counts + N;                      // N+1
  int* rank   = rowptr + N + 1;                  // E
  int* incl   = rank + E;                        // N
  int* blocksum = incl + N;                      // 256
  int* csr_src = blocksum + 256;                 // E
  float* pacc = (float*)(csr_src + E);           // N*C_OUT

  gru_evolve2_k<<<128 + nb, 256, 0, stream>>>(W1, wih1, whh1, bih1, bhh1,
                                              W2, wih2, whh2, bih2, bhh2,
                                              Bhi1, Bhi2, counts, N);

  count_rank_k<<<(E + 255) / 256, 256, 0, stream>>>(dst, counts, rank, E);
  scan_local_k<<<nb, SB, 0, stream>>>(counts, incl, blocksum, N);
  scan_finish_k<<<nb, SB, 0, stream>>>(counts, incl, blocksum, rowptr, dinv, N, nb);

  // layer 1 gemm + csr fill (independent; fused dispatch)
  fill_gemm_k<<<ngemm + nfill, 256, 0, stream>>>(x, Bhi1, dinv, plane0, plane1, N, ngemm,
                                                 src, dst, rank, rowptr, csr_src, E);
  agg_pass_k<0, 0><<<nagg, 256, 0, stream>>>(rowptr, csr_src, dinv, plane0, bufB,
                                             nullptr, nullptr, nullptr, nullptr, N);
  agg_pass_k<1, 0><<<nagg, 256, 0, stream>>>(rowptr, csr_src, dinv, plane1, bufB,
                                             nullptr, nullptr, nullptr, nullptr, N);

  // layer 2
  gemm_mfma_k<<<ngemm, 256, 0, stream>>>(bufB, Bhi2, dinv, plane0, plane1, N);
  agg_pass_k<0, 1><<<nagg, 256, 0, stream>>>(rowptr, csr_src, dinv, plane0, nullptr,
                                             lw, lb, pacc, nullptr, N);
  agg_pass_k<1, 2><<<nagg, 256, 0, stream>>>(rowptr, csr_src, dinv, plane1, nullptr,
                                             lw, lb, pacc, out, N);
}

// Round 15
// 259.255 us; speedup vs baseline: 1.2136x; 1.2136x over previous
//
#include <hip/hip_runtime.h>
#include <cstddef>
#include <cstdint>

#define F 128
#define C_OUT 10
#define SB 256   // scan block size

typedef short bf16x8 __attribute__((ext_vector_type(8)));
typedef float f32x4  __attribute__((ext_vector_type(4)));
typedef float f32x2  __attribute__((ext_vector_type(2)));

__device__ __forceinline__ unsigned short bf16_rne(float f) {
  unsigned u = __float_as_uint(f);
  return (unsigned short)((u + 0x7FFFu + ((u >> 16) & 1u)) >> 16);
}

// ---------------- GRU weight evolution (both layers, single-bf16 RNE) + zero counts ----
__global__ void gru_evolve2_k(const float* __restrict__ W01, const float* __restrict__ wih1,
                              const float* __restrict__ whh1, const float* __restrict__ bih1,
                              const float* __restrict__ bhh1,
                              const float* __restrict__ W02, const float* __restrict__ wih2,
                              const float* __restrict__ whh2, const float* __restrict__ bih2,
                              const float* __restrict__ bhh2,
                              unsigned short* __restrict__ Bhi1, unsigned short* __restrict__ Bhi2,
                              int* __restrict__ counts, int n) {
  if ((int)blockIdx.x >= 128) {
    int i = ((int)blockIdx.x - 128) * SB + threadIdx.x;
    if (i < n) counts[i] = 0;
    return;
  }
  int t = blockIdx.x * 256 + threadIdx.x;     // 0..32767
  int layer = t >> 14;
  int tt = t & 16383;
  const float* W0  = layer ? W02  : W01;
  const float* wih = layer ? wih2 : wih1;
  const float* whh = layer ? whh2 : whh1;
  const float* bih = layer ? bih2 : bih1;
  const float* bhh = layer ? bhh2 : bhh1;
  unsigned short* Bhi = layer ? Bhi2 : Bhi1;
  int i = tt >> 7, j = tt & 127;      // i = k (feature) index, j = w_col index
  const float4* w0r = (const float4*)(W0 + (size_t)i * F);
  float gi[3], gh[3];
#pragma unroll
  for (int g = 0; g < 3; ++g) {
    const float4* wr = (const float4*)(wih + (size_t)(g * F + j) * F);
    const float4* hr = (const float4*)(whh + (size_t)(g * F + j) * F);
    float si = 0.f, sh = 0.f;
    for (int k = 0; k < F / 4; ++k) {
      float4 a = w0r[k];
      float4 b = wr[k];
      float4 c = hr[k];
      si += a.x * b.x + a.y * b.y + a.z * b.z + a.w * b.w;
      sh += a.x * c.x + a.y * c.y + a.z * c.z + a.w * c.w;
    }
    gi[g] = si + bih[g * F + j];
    gh[g] = sh + bhh[g * F + j];
  }
  float r = 1.0f / (1.0f + expf(-(gi[0] + gh[0])));
  float z = 1.0f / (1.0f + expf(-(gi[1] + gh[1])));
  float nn = tanhf(gi[2] + r * gh[2]);
  float val = (1.0f - z) * nn + z * W0[(size_t)i * F + j];

  int kstep = i >> 5, kl = i & 31;
  int lane = (kl >> 3) * 16 + (j & 15);
  int tile = j >> 4;
  int idx = ((kstep * 8 + tile) * 64 + lane) * 8 + (kl & 7);
  Bhi[idx] = bf16_rne(val);
}

// ---------------- CSR build ----------------
__global__ void count_rank_k(const int* __restrict__ dst, int* __restrict__ counts,
                             int* __restrict__ rank, int E) {
  int e = blockIdx.x * blockDim.x + threadIdx.x;
  if (e < E) rank[e] = atomicAdd(&counts[dst[e]], 1);
}

__global__ void scan_local_k(const int* __restrict__ counts, int* __restrict__ incl,
                             int* __restrict__ blocksum, int n) {
  __shared__ int sh[SB];
  int gid = blockIdx.x * SB + threadIdx.x;
  int v = (gid < n) ? counts[gid] : 0;
  sh[threadIdx.x] = v;
  __syncthreads();
  for (int off = 1; off < SB; off <<= 1) {
    int t = 0;
    if ((int)threadIdx.x >= off) t = sh[threadIdx.x - off];
    __syncthreads();
    if ((int)threadIdx.x >= off) sh[threadIdx.x] += t;
    __syncthreads();
  }
  if (gid < n) incl[gid] = sh[threadIdx.x];
  if (threadIdx.x == SB - 1) blocksum[blockIdx.x] = sh[SB - 1];
}

__global__ void scan_finish_k(const int* __restrict__ counts, const int* __restrict__ incl,
                              const int* __restrict__ blocksum, int* __restrict__ rowptr,
                              float* __restrict__ dinv, int n, int nb) {
  __shared__ int sh[SB];
  __shared__ int orig[SB];
  int v = ((int)threadIdx.x < nb) ? blocksum[threadIdx.x] : 0;
  sh[threadIdx.x] = v;
  orig[threadIdx.x] = v;
  __syncthreads();
  for (int off = 1; off < SB; off <<= 1) {
    int t = 0;
    if ((int)threadIdx.x >= off) t = sh[threadIdx.x - off];
    __syncthreads();
    if ((int)threadIdx.x >= off) sh[threadIdx.x] += t;
    __syncthreads();
  }
  int myoff = sh[blockIdx.x] - orig[blockIdx.x];
  int gid = blockIdx.x * SB + threadIdx.x;
  if (gid >= n) return;
  int c = counts[gid];
  int inc = myoff + incl[gid];
  rowptr[gid] = inc - c;
  dinv[gid] = rsqrtf((float)c + 1.0f);
  if (gid == n - 1) rowptr[n] = inc;
}

// fill stores PRE-SHIFTED src (src<<7 = byte offset of the 128B fp8 row).
__device__ __forceinline__ void fill_body(int bid, const int* __restrict__ src,
                                          const int* __restrict__ dst,
                                          const int* __restrict__ rank,
                                          const int* __restrict__ rowptr,
                                          int* __restrict__ csr_src, int E) {
  int e = bid * 256 + (int)threadIdx.x;
  if (e < E) {
    int d = dst[e];
    csr_src[rowptr[d] + rank[e]] = src[e] << 7;
  }
}

// ---------------- MFMA GEMM: fp8 rows (128 B), single-bf16 inputs --------------------
// Transposed MFMA: D = W' (A) x X^T (B); lane owns x_row = lane&15, 4 consecutive
// w_cols per tile. Single-bf16 RNE inputs (verified: absmax unchanged vs split).
// Epilogue: fp8 e4m3 encode (HW cvt_pk_fp8_f32); row = 32 dwords = one cache line.
__device__ __forceinline__ void gemm_body(int bid, const float* __restrict__ X,
                                          const unsigned short* __restrict__ Bhi,
                                          const float* __restrict__ dinv,
                                          unsigned* __restrict__ Y, int nrows) {
  int wid = bid * 4 + ((int)threadIdx.x >> 6);
  int lane = threadIdx.x & 63;
  int ng = (nrows + 15) >> 4;
  if (wid >= ng) return;
  int g = __builtin_amdgcn_readfirstlane(wid);
  int q = lane >> 4, m = lane & 15;
  int rowA = g * 16 + m;
  if (rowA >= nrows) rowA = nrows - 1;

  f32x4 acc[8];
#pragma unroll
  for (int t = 0; t < 8; ++t) { acc[t].x = 0.f; acc[t].y = 0.f; acc[t].z = 0.f; acc[t].w = 0.f; }

#pragma unroll
  for (int s = 0; s < 4; ++s) {
    const float* xp = X + (size_t)rowA * F + s * 32 + q * 8;
    float4 xa = *(const float4*)xp;
    float4 xb = *(const float4*)(xp + 4);
    float xv[8] = {xa.x, xa.y, xa.z, xa.w, xb.x, xb.y, xb.z, xb.w};
    bf16x8 xh;
#pragma unroll
    for (int j = 0; j < 8; ++j) xh[j] = (short)bf16_rne(xv[j]);
#pragma unroll
    for (int t = 0; t < 8; ++t) {
      size_t boff = ((size_t)(s * 8 + t) * 64 + lane) * 8;
      bf16x8 wh = *(const bf16x8*)(Bhi + boff);
      acc[t] = __builtin_amdgcn_mfma_f32_16x16x32_bf16(wh, xh, acc[t], 0, 0, 0);
    }
  }

  int row = g * 16 + m;
  if (row < nrows) {
    float dd = dinv[row];
    unsigned* yr = Y + (size_t)row * 32 + q;   // lane q owns dword t*4+q
#pragma unroll
    for (int t = 0; t < 8; ++t) {
      int p = __builtin_amdgcn_cvt_pk_fp8_f32(dd * acc[t].x, dd * acc[t].y, 0, false);
      p = __builtin_amdgcn_cvt_pk_fp8_f32(dd * acc[t].z, dd * acc[t].w, p, true);
      yr[t * 4] = (unsigned)p;
    }
  }
}

__global__ void gemm_mfma_k(const float* __restrict__ X, const unsigned short* __restrict__ Bhi,
                            const float* __restrict__ dinv, unsigned* __restrict__ Y,
                            int nrows) {
  gemm_body(blockIdx.x, X, Bhi, dinv, Y, nrows);
}

// fused: blocks [0, ngemm) do layer-1 gemm; [ngemm, ...) do csr fill.
__global__ void fill_gemm_k(const float* __restrict__ X, const unsigned short* __restrict__ Bhi,
                            const float* __restrict__ dinv, unsigned* __restrict__ Y,
                            int nrows, int ngemm,
                            const int* __restrict__ src, const int* __restrict__ dst,
                            const int* __restrict__ rank, const int* __restrict__ rowptr,
                            int* __restrict__ csr_src, int E) {
  if ((int)blockIdx.x < ngemm)
    gemm_body(blockIdx.x, X, Bhi, dinv, Y, nrows);
  else
    fill_body((int)blockIdx.x - ngemm, src, dst, rank, rowptr, csr_src, E);
}

// ---------------- gather aggregation (R13 form): fp8 rows (128 B), half-wave --------
// One wave per node. Lanes 0-31 even edges, 32-63 odd edges; lane (half,hm) loads
// one dword = 4 fp8 cols {4hm..4hm+3}. csr entries PRE-SHIFTED byte offsets
// (row<<7). Decode via HW cvt_pk_f32_fp8. Epilogue: 4x shfl_xor(32).
template <bool FUSE_LOGITS>
__global__ void agg_fp8_k(const int* __restrict__ rowptr, const int* __restrict__ csr_src,
                          const float* __restrict__ dinv, const unsigned* __restrict__ xwp,
                          float* __restrict__ hout,
                          const float* __restrict__ lw, const float* __restrict__ lb,
                          float* __restrict__ outp, int n) {
  int wave = (int)((blockIdx.x * blockDim.x + threadIdx.x) >> 6);
  int lane = threadIdx.x & 63;
  if (wave >= n) return;
  int node = __builtin_amdgcn_readfirstlane(wave);
  int half = lane >> 5, hm = lane & 31;
  float dd = dinv[node];
  const char* __restrict__ cb = (const char*)xwp;   // row = 128 bytes
  unsigned loff = (unsigned)(hm << 2);
  f32x2 acc0 = {0.f, 0.f}, acc1 = {0.f, 0.f};
  f32x2 bcc0 = {0.f, 0.f}, bcc1 = {0.f, 0.f};

#define DEC(U, A, B)                                           \
  do {                                                         \
    (A) += __builtin_amdgcn_cvt_pk_f32_fp8((int)(U), false);   \
    (B) += __builtin_amdgcn_cvt_pk_f32_fp8((int)(U), true);    \
  } while (0)

  // self-loop (lower half only; upper half contributes 0)
  {
    unsigned u = *(const unsigned*)(cb + ((((unsigned)node) << 7) | loff));
    if (half) u = 0u;
    DEC(u, acc0, acc1);
  }

  int b = rowptr[node], e = rowptr[node + 1];
  int i = b;
  // 16-edge main loop: 8 dword loads in flight per wave
  for (; i + 16 <= e; i += 16) {
    int s0 = csr_src[i + 0],  s1 = csr_src[i + 1],  s2 = csr_src[i + 2],  s3 = csr_src[i + 3];
    int s4 = csr_src[i + 4],  s5 = csr_src[i + 5],  s6 = csr_src[i + 6],  s7 = csr_src[i + 7];
    int s8 = csr_src[i + 8],  s9 = csr_src[i + 9],  sA = csr_src[i + 10], sB = csr_src[i + 11];
    int sC = csr_src[i + 12], sD = csr_src[i + 13], sE = csr_src[i + 14], sF = csr_src[i + 15];
    unsigned o0 = ((unsigned)(half ? s1 : s0)) | loff;
    unsigned o1 = ((unsigned)(half ? s3 : s2)) | loff;
    unsigned o2 = ((unsigned)(half ? s5 : s4)) | loff;
    unsigned o3 = ((unsigned)(half ? s7 : s6)) | loff;
    unsigned o4 = ((unsigned)(half ? s9 : s8)) | loff;
    unsigned o5 = ((unsigned)(half ? sB : sA)) | loff;
    unsigned o6 = ((unsigned)(half ? sD : sC)) | loff;
    unsigned o7 = ((unsigned)(half ? sF : sE)) | loff;
    unsigned u0 = *(const unsigned*)(cb + o0);
    unsigned u1 = *(const unsigned*)(cb + o1);
    unsigned u2 = *(const unsigned*)(cb + o2);
    unsigned u3 = *(const unsigned*)(cb + o3);
    unsigned u4 = *(const unsigned*)(cb + o4);
    unsigned u5 = *(const unsigned*)(cb + o5);
    unsigned u6 = *(const unsigned*)(cb + o6);
    unsigned u7 = *(const unsigned*)(cb + o7);
    DEC(u0, acc0, acc1);
    DEC(u1, bcc0, bcc1);
    DEC(u2, acc0, acc1);
    DEC(u3, bcc0, bcc1);
    DEC(u4, acc0, acc1);
    DEC(u5, bcc0, bcc1);
    DEC(u6, acc0, acc1);
    DEC(u7, bcc0, bcc1);
  }
  // 8-edge tail
  for (; i + 8 <= e; i += 8) {
    int s0 = csr_src[i + 0], s1 = csr_src[i + 1], s2 = csr_src[i + 2], s3 = csr_src[i + 3];
    int s4 = csr_src[i + 4], s5 = csr_src[i + 5], s6 = csr_src[i + 6], s7 = csr_src[i + 7];
    unsigned o0 = ((unsigned)(half ? s1 : s0)) | loff;
    unsigned o1 = ((unsigned)(half ? s3 : s2)) | loff;
    unsigned o2 = ((unsigned)(half ? s5 : s4)) | loff;
    unsigned o3 = ((unsigned)(half ? s7 : s6)) | loff;
    unsigned u0 = *(const unsigned*)(cb + o0);
    unsigned u1 = *(const unsigned*)(cb + o1);
    unsigned u2 = *(const unsigned*)(cb + o2);
    unsigned u3 = *(const unsigned*)(cb + o3);
    DEC(u0, acc0, acc1);
    DEC(u1, bcc0, bcc1);
    DEC(u2, acc0, acc1);
    DEC(u3, bcc0, bcc1);
  }
  for (; i + 2 <= e; i += 2) {
    int s0 = csr_src[i], s1 = csr_src[i + 1];
    unsigned o = ((unsigned)(half ? s1 : s0)) | loff;
    unsigned u = *(const unsigned*)(cb + o);
    DEC(u, acc0, acc1);
  }
  if (i < e) {
    int s = csr_src[i];
    unsigned u = *(const unsigned*)(cb + (((unsigned)s) | loff));
    if (half) u = 0u;
    DEC(u, acc0, acc1);
  }
#undef DEC
  acc0 += bcc0;
  acc1 += bcc1;

  // combine the two halves (both end up with the full sum)
  acc0.x += __shfl_xor(acc0.x, 32);
  acc0.y += __shfl_xor(acc0.y, 32);
  acc1.x += __shfl_xor(acc1.x, 32);
  acc1.y += __shfl_xor(acc1.y, 32);

  float h0 = fmaxf(dd * acc0.x, 0.f);
  float h1 = fmaxf(dd * acc0.y, 0.f);
  float h2 = fmaxf(dd * acc1.x, 0.f);
  float h3 = fmaxf(dd * acc1.y, 0.f);

  if (!FUSE_LOGITS) {
    if (half == 0) {
      *(float4*)(hout + (size_t)node * F + hm * 4) = make_float4(h0, h1, h2, h3);
    }
  } else {
    float acc[C_OUT];
#pragma unroll
    for (int c = 0; c < C_OUT; ++c) {
      float4 w = *(const float4*)(lw + (size_t)c * F + hm * 4);
      float v = h0 * w.x + h1 * w.y + h2 * w.z + h3 * w.w;
      v += __shfl_xor(v, 1); v += __shfl_xor(v, 2);
      v += __shfl_xor(v, 4); v += __shfl_xor(v, 8);
      v += __shfl_xor(v, 16);
      acc[c] = v + lb[c];
    }
    float mx = acc[0];
#pragma unroll
    for (int c = 1; c < C_OUT; ++c) mx = fmaxf(mx, acc[c]);
    float s = 0.f;
#pragma unroll
    for (int c = 0; c < C_OUT; ++c) s += expf(acc[c] - mx);
    float lse = mx + logf(s);
#pragma unroll
    for (int c = 0; c < C_OUT; ++c)
      if (lane == c) outp[(size_t)node * C_OUT + c] = acc[c] - lse;
  }
}

extern "C" void kernel_launch(void* const* d_in, const int* in_sizes, int n_in,
                              void* d_out, int out_size, void* d_ws, size_t ws_size,
                              hipStream_t stream) {
  const float* x    = (const float*)d_in[0];
  const int*   ei   = (const int*)d_in[1];
  const float* W1   = (const float*)d_in[2];
  const float* wih1 = (const float*)d_in[3];
  const float* whh1 = (const float*)d_in[4];
  const float* bih1 = (const float*)d_in[5];
  const float* bhh1 = (const float*)d_in[6];
  const float* W2   = (const float*)d_in[7];
  const float* wih2 = (const float*)d_in[8];
  const float* whh2 = (const float*)d_in[9];
  const float* bih2 = (const float*)d_in[10];
  const float* bhh2 = (const float*)d_in[11];
  const float* lw   = (const float*)d_in[12];
  const float* lb   = (const float*)d_in[13];
  float* out = (float*)d_out;

  int N = in_sizes[0] / F;
  int E = in_sizes[1] / 2;
  const int* src = ei;
  const int* dst = ei + E;
  int nb = (N + SB - 1) / SB;   // 196 (must be <= 256)
  int ng = (N + 15) / 16;
  int ngemm = (ng + 3) / 4;
  int nfill = (E + 255) / 256;
  int nagg = (N + 3) / 4;

  float* ws = (float*)d_ws;
  unsigned* bufA = (unsigned*)ws;                // N*32 dwords (fp8 rows, 128 B)
  float* bufB = (float*)(bufA + (size_t)N * 32); // N*F floats (h)
  float* dinv = bufB + (size_t)N * F;            // N
  unsigned short* Bhi1 = (unsigned short*)(dinv + N);  // 16384
  unsigned short* Bhi2 = Bhi1 + F * F;                 // 16384
  int* counts = (int*)(Bhi2 + F * F);            // N
  int* rowptr = counts + N;                      // N+1
  int* rank   = rowptr + N + 1;                  // E
  int* incl   = rank + E;                        // N
  int* blocksum = incl + N;                      // 256
  int* csr_src = blocksum + 256;                 // E

  gru_evolve2_k<<<128 + nb, 256, 0, stream>>>(W1, wih1, whh1, bih1, bhh1,
                                              W2, wih2, whh2, bih2, bhh2,
                                              Bhi1, Bhi2, counts, N);

  count_rank_k<<<(E + 255) / 256, 256, 0, stream>>>(dst, counts, rank, E);
  scan_local_k<<<nb, SB, 0, stream>>>(counts, incl, blocksum, N);
  scan_finish_k<<<nb, SB, 0, stream>>>(counts, incl, blocksum, rowptr, dinv, N, nb);

  // layer 1 gemm + csr fill (independent; fused dispatch)
  fill_gemm_k<<<ngemm + nfill, 256, 0, stream>>>(x, Bhi1, dinv, bufA, N, ngemm,
                                                 src, dst, rank, rowptr, csr_src, E);
  agg_fp8_k<false><<<nagg, 256, 0, stream>>>(rowptr, csr_src, dinv, bufA, bufB,
                                             nullptr, nullptr, nullptr, N);

  // layer 2 (logits fused)
  gemm_mfma_k<<<ngemm, 256, 0, stream>>>(bufB, Bhi2, dinv, bufA, N);
  agg_fp8_k<true><<<nagg, 256, 0, stream>>>(rowptr, csr_src, dinv, bufA, nullptr,
                                            lw, lb, out, N);
}